// Round 6
// baseline (291.781 us; speedup 1.0000x reference)
//
#include <hip/hip_runtime.h>
#include <math.h>

// Problem constants (B=64, J=17, H=W=128)
#define BJ    1088               // B*J maps per tensor
#define NMAP  (2 * BJ)           // 2176 maps (pred then gt)
#define HW    16384              // 128*128
#define NTH   512                // 8 waves per block
#define NWAVE (NTH / 64)
#define F4PT  (HW / 4 / NTH)     // 8 float4 per thread

// Monotonic unsigned key for float bits: orders like float compare.
__device__ __forceinline__ unsigned int ford(unsigned int u) {
    return (u & 0x80000000u) ? ~u : (u | 0x80000000u);
}
__device__ __forceinline__ unsigned int ford_inv(unsigned int o) {
    return (o & 0x80000000u) ? (o & 0x7fffffffu) : ~o;
}

// R14 = R9's proven 2176-block single-map body (52.2 µs: fine granularity
// gives best dynamic load-balance; FETCH=1 sweep, zero spill, 4 blocks/CU)
// + single-launch pairing via last-arriver protocol (R13 post-mortem:
// pair-per-block fusion coarsened granularity and cost 6 µs; this keeps
// block granularity at one map).
// Protocol (device-scope, XCD-safe): publish d[m] with atomicExch,
// __threadfence, bump pair counter; second arriver computes |dG-dP|,
// atomicAdds scaled diff into ws accumulator, fence, bumps global counter;
// the 1088th pair-finisher snapshots the accumulator into out.
// ws layout: [0]=acc f32, [1]=g u32, [2..1089]=cnt u32, [1090..3265]=d f32.
__global__ __launch_bounds__(NTH, 8) void hm_stats_pair(const float* __restrict__ outp,
                                                        const float* __restrict__ tgtp,
                                                        float* __restrict__ ws,
                                                        float* __restrict__ out)
{
    __shared__ unsigned long long rk[NWAVE];
    __shared__ float rs[NWAVE], rc[NWAVE];

    const int m = blockIdx.x;                      // [0, NMAP)
    const int t = threadIdx.x;
    const float* __restrict__ src = (m < BJ)
        ? (outp + (size_t)m * HW)
        : (tgtp + (size_t)(m - BJ) * HW);
    const float4* __restrict__ s4 = (const float4*)src;

    // ---- single load burst (8 float4 outstanding), 4-chain max scan
    float4 v[F4PT];
#pragma unroll
    for (int k = 0; k < F4PT; ++k) v[k] = s4[t + k * NTH];

    float mx0 = -INFINITY, mx1 = -INFINITY, mx2 = -INFINITY, mx3 = -INFINITY;
    int   ix0 = 0, ix1 = 1, ix2 = 2, ix3 = 3;
#pragma unroll
    for (int k = 0; k < F4PT; ++k) {               // idx grows with k -> '>' keeps first
        const int base = (t + k * NTH) << 2;
        if (v[k].x > mx0) { mx0 = v[k].x; ix0 = base;     }
        if (v[k].y > mx1) { mx1 = v[k].y; ix1 = base + 1; }
        if (v[k].z > mx2) { mx2 = v[k].z; ix2 = base + 2; }
        if (v[k].w > mx3) { mx3 = v[k].w; ix3 = base + 3; }
    }

    // merge 4 chains via u64 keys: (ord(val)<<32)|~idx — max = (max val, min idx)
    unsigned long long k0 = ((unsigned long long)ford(__float_as_uint(mx0)) << 32) | (unsigned int)~ix0;
    unsigned long long k1 = ((unsigned long long)ford(__float_as_uint(mx1)) << 32) | (unsigned int)~ix1;
    unsigned long long k2 = ((unsigned long long)ford(__float_as_uint(mx2)) << 32) | (unsigned int)~ix2;
    unsigned long long k3 = ((unsigned long long)ford(__float_as_uint(mx3)) << 32) | (unsigned int)~ix3;
    unsigned long long key = k0 > k1 ? k0 : k1;
    key = k2 > key ? k2 : key;
    key = k3 > key ? k3 : key;
#pragma unroll
    for (int off = 32; off >= 1; off >>= 1) {
        const unsigned long long ok = __shfl_xor(key, off, 64);
        key = (ok > key) ? ok : key;
    }
    const int wave = t >> 6, lane = t & 63;
    if (lane == 0) rk[wave] = key;
    __syncthreads();
    unsigned long long bkey = rk[0];
#pragma unroll
    for (int w = 1; w < NWAVE; ++w) bkey = (rk[w] > bkey) ? rk[w] : bkey;

    const float maxv = __uint_as_float(ford_inv((unsigned int)(bkey >> 32)));
    const int   midx = (int)~(unsigned int)(bkey & 0xffffffffu);
    const float ym  = (float)(midx >> 7);          // reference: idx // H (H=128 stride)
    const float xm  = (float)(midx & 127);
    const float thv = maxv * 0.5f;

    // ---- masked distance sum from v[] (register-kept or cache-hit reload;
    // R9 proved this shape stays at one HBM sweep with no spill)
    float s = 0.0f, c = 0.0f;
#pragma unroll
    for (int k = 0; k < F4PT; ++k) {
        const float4 w = v[k];
        const int g4 = t + k * NTH;
        const float dy  = (float)(g4 >> 5) - ym;   // all 4 elems share a row
        const float dy2 = dy * dy;
        const float cb  = (float)((g4 << 2) & 127) - xm;
        {
            const float dx = cb;        const float ds = __builtin_amdgcn_sqrtf(fmaf(dx, dx, dy2));
            const float mk = (w.x > thv) ? 1.0f : 0.0f;  s = fmaf(mk, ds, s);  c += mk;
        }
        {
            const float dx = cb + 1.0f; const float ds = __builtin_amdgcn_sqrtf(fmaf(dx, dx, dy2));
            const float mk = (w.y > thv) ? 1.0f : 0.0f;  s = fmaf(mk, ds, s);  c += mk;
        }
        {
            const float dx = cb + 2.0f; const float ds = __builtin_amdgcn_sqrtf(fmaf(dx, dx, dy2));
            const float mk = (w.z > thv) ? 1.0f : 0.0f;  s = fmaf(mk, ds, s);  c += mk;
        }
        {
            const float dx = cb + 3.0f; const float ds = __builtin_amdgcn_sqrtf(fmaf(dx, dx, dy2));
            const float mk = (w.w > thv) ? 1.0f : 0.0f;  s = fmaf(mk, ds, s);  c += mk;
        }
    }

#pragma unroll
    for (int off = 32; off >= 1; off >>= 1) {
        s += __shfl_xor(s, off, 64);
        c += __shfl_xor(c, off, 64);
    }
    if (lane == 0) { rs[wave] = s; rc[wave] = c; }
    __syncthreads();
    if (t == 0) {
#pragma unroll
        for (int w = 1; w < NWAVE; ++w) { s += rs[w]; c += rc[w]; }
        const float mean = s / fmaxf(c, 1.0f);
        const float d0   = (c > 0.0f) ? (mean / 181.02f) : 1.0f;   // MAX_DIST
        const float dd   = (maxv > 0.0f) ? d0 : 0.0f;

        // ---- last-arriver pairing (all device-scope)
        float*        acc  = ws;                           // [0]
        unsigned int* g    = (unsigned int*)(ws + 1);      // [1]
        unsigned int* cnt  = (unsigned int*)(ws + 2);      // [2..1089]
        float*        dArr = ws + 2 + BJ;                  // [1090..3265]

        const int p  = (m < BJ) ? m : m - BJ;              // pair index
        const int om = (m < BJ) ? m + BJ : m - BJ;         // partner map

        atomicExch(&dArr[m], dd);                          // publish (coherent)
        __threadfence();                                   // d visible before count
        if (atomicAdd(&cnt[p], 1u) == 1u) {                // second arriver
            const float dOther = atomicAdd(&dArr[om], 0.0f);   // coherent read
            atomicAdd(acc, fabsf(dd - dOther) * (1.0f / (17.0f * 64.0f)));
            __threadfence();                               // acc add performed before g add
            if (atomicAdd(g, 1u) == (unsigned int)(BJ - 1)) {
                out[0] = atomicAdd(acc, 0.0f);             // 1088th pair: snapshot total
            }
        }
    }
}

extern "C" void kernel_launch(void* const* d_in, const int* in_sizes, int n_in,
                              void* d_out, int out_size, void* d_ws, size_t ws_size,
                              hipStream_t stream) {
    const float* outp = (const float*)d_in[0];     // [64,17,128,128] f32
    const float* tgtp = (const float*)d_in[1];
    float* ws = (float*)d_ws;

    // zero acc + g + cnt[1088]  (d[] region needs no init: written before read)
    hipMemsetAsync(d_ws, 0, (2 + BJ) * sizeof(float), stream);
    hm_stats_pair<<<dim3(NMAP), dim3(NTH), 0, stream>>>(outp, tgtp, ws, (float*)d_out);
}

// Round 7
// 161.972 us; speedup vs baseline: 1.8014x; 1.8014x over previous
//
#include <hip/hip_runtime.h>
#include <math.h>

// Problem constants (B=64, J=17, H=W=128)
#define BJ    1088               // B*J map-pairs (pred_m paired with gt_m)
#define HW    16384              // 128*128
#define NTH   512                // 8 waves per block
#define NWAVE (NTH / 64)
#define F4PT  (HW / 4 / NTH)     // 8 float4 per thread per map

// Monotonic unsigned key for float bits: orders like float compare.
__device__ __forceinline__ unsigned int ford(unsigned int u) {
    return (u & 0x80000000u) ? ~u : (u | 0x80000000u);
}
__device__ __forceinline__ unsigned int ford_inv(unsigned int o) {
    return (o & 0x80000000u) ? (o & 0x7fffffffu) : ~o;
}

// R15: front-loaded pair kernel.
//  - R13's loss vs R9 (58.5 vs 52.2) was the mid-block memory hole: map B's
//    loads issued only after map A's full compute+barrier pipeline. Here the
//    block's ENTIRE 128 KB demand issues up front: A -> registers (R9's
//    spill-free shape), B -> LDS via global_load_lds (zero VGPR cost).
//  - Barriers are raw s_barrier + lgkmcnt(0)-only: __syncthreads would drain
//    vmcnt(0) and serialize against B's in-flight loads (the m97 barrier-drain
//    stall). B's LDS slots are each wave's OWN global_load_lds destinations
//    (dest = wave-uniform base + lane*16), so a per-wave vmcnt(0) makes them
//    readable with no barrier.
//  - One launch, one atomicAdd per block. NO fences / cross-block protocol
//    (R14: device-scope fences poisoned the caches, 3.5x regression).
//  - __launch_bounds__(512,4) -> 128-VGPR cap (no spill possible);
//    64 KB LDS -> 2 blocks/CU, same 2.125 residency waves as R7/R13.
__global__ __launch_bounds__(NTH, 4) void hm_pair(const float* __restrict__ outp,
                                                  const float* __restrict__ tgtp,
                                                  float* __restrict__ out)
{
    __shared__ float hmB[HW];                      // 64 KB: map B staging
    __shared__ unsigned long long rkA[NWAVE], rkB[NWAVE];
    __shared__ float rsA[NWAVE], rcA[NWAVE], rsB[NWAVE], rcB[NWAVE];

    const int m = blockIdx.x;                      // [0, BJ)
    const int t = threadIdx.x;
    const int wave = t >> 6, lane = t & 63;
    const float4* __restrict__ a4 = (const float4*)(outp + (size_t)m * HW);
    const float4* __restrict__ b4 = (const float4*)(tgtp + (size_t)m * HW);
    float4* hmB4 = (float4*)hmB;

    // ---- front-load ALL demand: A burst to regs, B burst direct to LDS
    float4 v[F4PT];
#pragma unroll
    for (int k = 0; k < F4PT; ++k) v[k] = a4[t + k * NTH];
#pragma unroll
    for (int k = 0; k < F4PT; ++k) {
        // dest is wave-uniform; lane's 16B lands at dest + lane*16
        __builtin_amdgcn_global_load_lds(
            (const __attribute__((address_space(1))) void*)(b4 + t + k * NTH),
            (__attribute__((address_space(3))) void*)(hmB4 + k * NTH + (t & ~63)),
            16, 0, 0);
    }

    // ================= map A (registers) =================
    float mx0 = -INFINITY, mx1 = -INFINITY, mx2 = -INFINITY, mx3 = -INFINITY;
    int   ix0 = 0, ix1 = 1, ix2 = 2, ix3 = 3;
#pragma unroll
    for (int k = 0; k < F4PT; ++k) {               // idx grows with k -> '>' keeps first
        const int base = (t + k * NTH) << 2;
        if (v[k].x > mx0) { mx0 = v[k].x; ix0 = base;     }
        if (v[k].y > mx1) { mx1 = v[k].y; ix1 = base + 1; }
        if (v[k].z > mx2) { mx2 = v[k].z; ix2 = base + 2; }
        if (v[k].w > mx3) { mx3 = v[k].w; ix3 = base + 3; }
    }
    unsigned long long k0 = ((unsigned long long)ford(__float_as_uint(mx0)) << 32) | (unsigned int)~ix0;
    unsigned long long k1 = ((unsigned long long)ford(__float_as_uint(mx1)) << 32) | (unsigned int)~ix1;
    unsigned long long k2 = ((unsigned long long)ford(__float_as_uint(mx2)) << 32) | (unsigned int)~ix2;
    unsigned long long k3 = ((unsigned long long)ford(__float_as_uint(mx3)) << 32) | (unsigned int)~ix3;
    unsigned long long key = k0 > k1 ? k0 : k1;
    key = k2 > key ? k2 : key;
    key = k3 > key ? k3 : key;
#pragma unroll
    for (int off = 32; off >= 1; off >>= 1) {
        const unsigned long long ok = __shfl_xor(key, off, 64);
        key = (ok > key) ? ok : key;
    }
    if (lane == 0) rkA[wave] = key;
    // barrier 1: lgkm-only (keeps B's global_load_lds in flight)
    asm volatile("s_waitcnt lgkmcnt(0)" ::: "memory");
    __builtin_amdgcn_s_barrier();
    unsigned long long bkey = rkA[0];
#pragma unroll
    for (int w = 1; w < NWAVE; ++w) bkey = (rkA[w] > bkey) ? rkA[w] : bkey;

    const float maxvA = __uint_as_float(ford_inv((unsigned int)(bkey >> 32)));
    const int   midxA = (int)~(unsigned int)(bkey & 0xffffffffu);
    {
        const float ym  = (float)(midxA >> 7);     // reference: idx // H (H=128 stride)
        const float xm  = (float)(midxA & 127);
        const float thv = maxvA * 0.5f;
        float s = 0.0f, c = 0.0f;
#pragma unroll
        for (int k = 0; k < F4PT; ++k) {
            const float4 w = v[k];
            const int g4 = t + k * NTH;
            const float dy  = (float)(g4 >> 5) - ym;
            const float dy2 = dy * dy;
            const float cb  = (float)((g4 << 2) & 127) - xm;
            {
                const float dx = cb;        const float ds = __builtin_amdgcn_sqrtf(fmaf(dx, dx, dy2));
                const float mk = (w.x > thv) ? 1.0f : 0.0f;  s = fmaf(mk, ds, s);  c += mk;
            }
            {
                const float dx = cb + 1.0f; const float ds = __builtin_amdgcn_sqrtf(fmaf(dx, dx, dy2));
                const float mk = (w.y > thv) ? 1.0f : 0.0f;  s = fmaf(mk, ds, s);  c += mk;
            }
            {
                const float dx = cb + 2.0f; const float ds = __builtin_amdgcn_sqrtf(fmaf(dx, dx, dy2));
                const float mk = (w.z > thv) ? 1.0f : 0.0f;  s = fmaf(mk, ds, s);  c += mk;
            }
            {
                const float dx = cb + 3.0f; const float ds = __builtin_amdgcn_sqrtf(fmaf(dx, dx, dy2));
                const float mk = (w.w > thv) ? 1.0f : 0.0f;  s = fmaf(mk, ds, s);  c += mk;
            }
        }
#pragma unroll
        for (int off = 32; off >= 1; off >>= 1) {
            s += __shfl_xor(s, off, 64);
            c += __shfl_xor(c, off, 64);
        }
        if (lane == 0) { rsA[wave] = s; rcA[wave] = c; }
    }
    // v[] dead here.

    // ================= map B (LDS, own-wave slots) =================
    asm volatile("s_waitcnt vmcnt(0)" ::: "memory");   // this wave's B loads landed
    __builtin_amdgcn_sched_barrier(0);
    {
        float mx0b = -INFINITY, mx1b = -INFINITY, mx2b = -INFINITY, mx3b = -INFINITY;
        int   jx0 = 0, jx1 = 1, jx2 = 2, jx3 = 3;
#pragma unroll
        for (int k = 0; k < F4PT; ++k) {
            const float4 w = hmB4[t + k * NTH];
            const int base = (t + k * NTH) << 2;
            if (w.x > mx0b) { mx0b = w.x; jx0 = base;     }
            if (w.y > mx1b) { mx1b = w.y; jx1 = base + 1; }
            if (w.z > mx2b) { mx2b = w.z; jx2 = base + 2; }
            if (w.w > mx3b) { mx3b = w.w; jx3 = base + 3; }
        }
        unsigned long long q0 = ((unsigned long long)ford(__float_as_uint(mx0b)) << 32) | (unsigned int)~jx0;
        unsigned long long q1 = ((unsigned long long)ford(__float_as_uint(mx1b)) << 32) | (unsigned int)~jx1;
        unsigned long long q2 = ((unsigned long long)ford(__float_as_uint(mx2b)) << 32) | (unsigned int)~jx2;
        unsigned long long q3 = ((unsigned long long)ford(__float_as_uint(mx3b)) << 32) | (unsigned int)~jx3;
        unsigned long long qk = q0 > q1 ? q0 : q1;
        qk = q2 > qk ? q2 : qk;
        qk = q3 > qk ? q3 : qk;
#pragma unroll
        for (int off = 32; off >= 1; off >>= 1) {
            const unsigned long long ok = __shfl_xor(qk, off, 64);
            qk = (ok > qk) ? ok : qk;
        }
        if (lane == 0) rkB[wave] = qk;
    }
    // barrier 2: lgkm-only (also publishes rsA/rcA for the epilogue)
    asm volatile("s_waitcnt lgkmcnt(0)" ::: "memory");
    __builtin_amdgcn_s_barrier();
    unsigned long long bkB = rkB[0];
#pragma unroll
    for (int w = 1; w < NWAVE; ++w) bkB = (rkB[w] > bkB) ? rkB[w] : bkB;

    const float maxvB = __uint_as_float(ford_inv((unsigned int)(bkB >> 32)));
    const int   midxB = (int)~(unsigned int)(bkB & 0xffffffffu);
    {
        const float ym  = (float)(midxB >> 7);
        const float xm  = (float)(midxB & 127);
        const float thv = maxvB * 0.5f;
        float s = 0.0f, c = 0.0f;
#pragma unroll
        for (int k = 0; k < F4PT; ++k) {
            const float4 w = hmB4[t + k * NTH];    // own slots, 2-way LDS alias free
            const int g4 = t + k * NTH;
            const float dy  = (float)(g4 >> 5) - ym;
            const float dy2 = dy * dy;
            const float cb  = (float)((g4 << 2) & 127) - xm;
            {
                const float dx = cb;        const float ds = __builtin_amdgcn_sqrtf(fmaf(dx, dx, dy2));
                const float mk = (w.x > thv) ? 1.0f : 0.0f;  s = fmaf(mk, ds, s);  c += mk;
            }
            {
                const float dx = cb + 1.0f; const float ds = __builtin_amdgcn_sqrtf(fmaf(dx, dx, dy2));
                const float mk = (w.y > thv) ? 1.0f : 0.0f;  s = fmaf(mk, ds, s);  c += mk;
            }
            {
                const float dx = cb + 2.0f; const float ds = __builtin_amdgcn_sqrtf(fmaf(dx, dx, dy2));
                const float mk = (w.z > thv) ? 1.0f : 0.0f;  s = fmaf(mk, ds, s);  c += mk;
            }
            {
                const float dx = cb + 3.0f; const float ds = __builtin_amdgcn_sqrtf(fmaf(dx, dx, dy2));
                const float mk = (w.w > thv) ? 1.0f : 0.0f;  s = fmaf(mk, ds, s);  c += mk;
            }
        }
#pragma unroll
        for (int off = 32; off >= 1; off >>= 1) {
            s += __shfl_xor(s, off, 64);
            c += __shfl_xor(c, off, 64);
        }
        if (lane == 0) { rsB[wave] = s; rcB[wave] = c; }
    }
    // barrier 3: publish rsB/rcB
    asm volatile("s_waitcnt lgkmcnt(0)" ::: "memory");
    __builtin_amdgcn_s_barrier();

    if (t == 0) {
        float sA = rsA[0], cA = rcA[0], sB = rsB[0], cB = rcB[0];
#pragma unroll
        for (int w = 1; w < NWAVE; ++w) {
            sA += rsA[w]; cA += rcA[w]; sB += rsB[w]; cB += rcB[w];
        }
        const float meanA = sA / fmaxf(cA, 1.0f);
        const float dA0   = (cA > 0.0f) ? (meanA / 181.02f) : 1.0f;   // MAX_DIST
        const float dP    = (maxvA > 0.0f) ? dA0 : 0.0f;
        const float meanB = sB / fmaxf(cB, 1.0f);
        const float dB0   = (cB > 0.0f) ? (meanB / 181.02f) : 1.0f;
        const float dG    = (maxvB > 0.0f) ? dB0 : 0.0f;
        atomicAdd(out, fabsf(dG - dP) * (1.0f / (17.0f * 64.0f)));
    }
}

extern "C" void kernel_launch(void* const* d_in, const int* in_sizes, int n_in,
                              void* d_out, int out_size, void* d_ws, size_t ws_size,
                              hipStream_t stream) {
    const float* outp = (const float*)d_in[0];     // [64,17,128,128] f32
    const float* tgtp = (const float*)d_in[1];

    hipMemsetAsync(d_out, 0, sizeof(float), stream);
    hm_pair<<<dim3(BJ), dim3(NTH), 0, stream>>>(outp, tgtp, (float*)d_out);
}

// Round 9
// 155.884 us; speedup vs baseline: 1.8718x; 1.0391x over previous
//
#include <hip/hip_runtime.h>
#include <math.h>

// Problem constants (B=64, J=17, H=W=128)
#define BJ    1088               // B*J maps per tensor
#define NMAP  (2 * BJ)           // 2176 maps (pred then gt)
#define HW    16384              // 128*128
#define NTH   512                // 8 waves per block
#define NWAVE (NTH / 64)
#define F4PT  (HW / 4 / NTH)     // 8 float4 per thread

// Monotonic unsigned key for float bits: orders like float compare.
__device__ __forceinline__ unsigned int ford(unsigned int u) {
    return (u & 0x80000000u) ? ~u : (u | 0x80000000u);
}
__device__ __forceinline__ unsigned int ford_inv(unsigned int o) {
    return (o & 0x80000000u) ? (o & 0x7fffffffu) : ~o;
}

// FINAL (revert to R7, the best harness-verified version: 155.98 µs total,
// 52.6 µs kernel). Session R9-R15 ledger: fine-granularity (one map per
// 512-thread block) + two trivial kernels beats every fusion variant:
//   R10/R11 pair-fused reg-kept: VGPR spill (54-59 MB scratch), 85-95 µs
//   R12 explicit re-read: FETCH doubled to 147 MB (L3 did NOT absorb), 71 µs
//   R13 pair-block sequential: coarser granularity, load-balance loss, 58.5 µs
//   R14 last-arriver atomics+fences: cache poisoning, 186 µs
//   R15 front-loaded gload_lds pair: 70.9 µs
// One 512-thread block per map, ONE HBM sweep guaranteed by explicit LDS
// staging; one data barrier (key exchange); masked sum re-reads each
// thread's OWN staged LDS values; 66 KB LDS -> 2 blocks/CU and the
// co-resident block's load burst hides this block's reduce/sum tail.
// (Round 8 was an infra failure — container died; identical resubmit.)
__global__ __launch_bounds__(NTH, 4) void hm_stats(const float* __restrict__ outp,
                                                   const float* __restrict__ tgtp,
                                                   float* __restrict__ d)
{
    __shared__ float hm[HW];                       // 64 KB
    __shared__ unsigned long long rk[NWAVE];
    __shared__ float rs[NWAVE], rc[NWAVE];

    const int m = blockIdx.x;                      // [0, NMAP)
    const int t = threadIdx.x;
    const float* __restrict__ src = (m < BJ)
        ? (outp + (size_t)m * HW)
        : (tgtp + (size_t)(m - BJ) * HW);
    const float4* __restrict__ s4 = (const float4*)src;
    float4* hm4 = (float4*)hm;

    // ---- single load burst (8 float4 outstanding), then stage + 4-chain scan
    float4 v[F4PT];
#pragma unroll
    for (int k = 0; k < F4PT; ++k) v[k] = s4[t + k * NTH];

    float mx0 = -INFINITY, mx1 = -INFINITY, mx2 = -INFINITY, mx3 = -INFINITY;
    int   ix0 = 0, ix1 = 1, ix2 = 2, ix3 = 3;
#pragma unroll
    for (int k = 0; k < F4PT; ++k) {               // per-thread idx grows with k -> '>' keeps first
        hm4[t + k * NTH] = v[k];
        const int base = (t + k * NTH) << 2;
        if (v[k].x > mx0) { mx0 = v[k].x; ix0 = base;     }
        if (v[k].y > mx1) { mx1 = v[k].y; ix1 = base + 1; }
        if (v[k].z > mx2) { mx2 = v[k].z; ix2 = base + 2; }
        if (v[k].w > mx3) { mx3 = v[k].w; ix3 = base + 3; }
    }

    // merge 4 chains via u64 keys: (ord(val)<<32)|~idx — max = (max val, min idx)
    unsigned long long k0 = ((unsigned long long)ford(__float_as_uint(mx0)) << 32) | (unsigned int)~ix0;
    unsigned long long k1 = ((unsigned long long)ford(__float_as_uint(mx1)) << 32) | (unsigned int)~ix1;
    unsigned long long k2 = ((unsigned long long)ford(__float_as_uint(mx2)) << 32) | (unsigned int)~ix2;
    unsigned long long k3 = ((unsigned long long)ford(__float_as_uint(mx3)) << 32) | (unsigned int)~ix3;
    unsigned long long key = k0 > k1 ? k0 : k1;
    key = k2 > key ? k2 : key;
    key = k3 > key ? k3 : key;
#pragma unroll
    for (int off = 32; off >= 1; off >>= 1) {
        const unsigned long long ok = __shfl_xor(key, off, 64);
        key = (ok > key) ? ok : key;
    }
    const int wave = t >> 6, lane = t & 63;
    if (lane == 0) rk[wave] = key;
    __syncthreads();                               // the ONLY data barrier
    unsigned long long bkey = rk[0];
#pragma unroll
    for (int w = 1; w < NWAVE; ++w) bkey = (rk[w] > bkey) ? rk[w] : bkey;

    const float maxv = __uint_as_float(ford_inv((unsigned int)(bkey >> 32)));
    const int   midx = (int)~(unsigned int)(bkey & 0xffffffffu);
    const float ym  = (float)(midx >> 7);          // reference: idx // H (H=128 stride)
    const float xm  = (float)(midx & 127);
    const float thv = maxv * 0.5f;

    // ---- masked distance sum from own staged LDS values (no 2nd barrier;
    // 2-way LDS aliasing is free)
    float s = 0.0f, c = 0.0f;
#pragma unroll
    for (int k = 0; k < F4PT; ++k) {
        const float4 w = hm4[t + k * NTH];
        const int g4 = t + k * NTH;
        const float dy  = (float)(g4 >> 5) - ym;   // all 4 elems share a row
        const float dy2 = dy * dy;
        const float cb  = (float)((g4 << 2) & 127) - xm;
        {
            const float dx = cb;        const float ds = __builtin_amdgcn_sqrtf(fmaf(dx, dx, dy2));
            const float mk = (w.x > thv) ? 1.0f : 0.0f;  s = fmaf(mk, ds, s);  c += mk;
        }
        {
            const float dx = cb + 1.0f; const float ds = __builtin_amdgcn_sqrtf(fmaf(dx, dx, dy2));
            const float mk = (w.y > thv) ? 1.0f : 0.0f;  s = fmaf(mk, ds, s);  c += mk;
        }
        {
            const float dx = cb + 2.0f; const float ds = __builtin_amdgcn_sqrtf(fmaf(dx, dx, dy2));
            const float mk = (w.z > thv) ? 1.0f : 0.0f;  s = fmaf(mk, ds, s);  c += mk;
        }
        {
            const float dx = cb + 3.0f; const float ds = __builtin_amdgcn_sqrtf(fmaf(dx, dx, dy2));
            const float mk = (w.w > thv) ? 1.0f : 0.0f;  s = fmaf(mk, ds, s);  c += mk;
        }
    }

#pragma unroll
    for (int off = 32; off >= 1; off >>= 1) {
        s += __shfl_xor(s, off, 64);
        c += __shfl_xor(c, off, 64);
    }
    if (lane == 0) { rs[wave] = s; rc[wave] = c; }
    __syncthreads();
    if (t == 0) {
#pragma unroll
        for (int w = 1; w < NWAVE; ++w) { s += rs[w]; c += rc[w]; }
        const float mean = s / fmaxf(c, 1.0f);
        const float dd   = (c > 0.0f) ? (mean / 181.02f) : 1.0f;   // MAX_DIST
        d[m] = (maxv > 0.0f) ? dd : 0.0f;
    }
}

// Single-block final reduction: sum |gt - pred| / J / B
__global__ __launch_bounds__(256) void finalize(const float* __restrict__ d,
                                                float* __restrict__ out)
{
    __shared__ float rs[4];
    const int t = threadIdx.x;
    float acc = 0.0f;
    for (int i = t; i < BJ; i += 256)
        acc += fabsf(d[BJ + i] - d[i]);
#pragma unroll
    for (int off = 32; off >= 1; off >>= 1)
        acc += __shfl_down(acc, off, 64);
    const int wave = t >> 6, lane = t & 63;
    if (lane == 0) rs[wave] = acc;
    __syncthreads();
    if (t == 0) {
        acc = rs[0] + rs[1] + rs[2] + rs[3];
        out[0] = acc / 17.0f / 64.0f;              // / J / B, reference order
    }
}

extern "C" void kernel_launch(void* const* d_in, const int* in_sizes, int n_in,
                              void* d_out, int out_size, void* d_ws, size_t ws_size,
                              hipStream_t stream) {
    const float* outp = (const float*)d_in[0];     // [64,17,128,128] f32
    const float* tgtp = (const float*)d_in[1];
    float* d = (float*)d_ws;                       // NMAP floats

    hm_stats<<<dim3(NMAP), dim3(NTH), 0, stream>>>(outp, tgtp, d);
    finalize<<<dim3(1),    dim3(256), 0, stream>>>(d, (float*)d_out);
}